// Round 1
// baseline (120.273 us; speedup 1.0000x reference)
//
#include <hip/hip_runtime.h>
#include <math.h>

#define K_DIM 4096
#define N_DIM 4096

// ---------------- Kernel 1: c[k] = sum_n W[k][n] ----------------
// One block per row of W (K rows), 256 threads, float4 loads.
__global__ void __launch_bounds__(256) colsum_kernel(const float* __restrict__ W,
                                                     float* __restrict__ c) {
    const int k = blockIdx.x;
    const float4* row = reinterpret_cast<const float4*>(W + (size_t)k * N_DIM);
    const int t = threadIdx.x;
    float acc = 0.f;
#pragma unroll
    for (int i = 0; i < N_DIM / 4 / 256; ++i) {   // 4 iterations
        float4 v = row[t + i * 256];
        acc += (v.x + v.y) + (v.z + v.w);
    }
    // wave64 reduce
#pragma unroll
    for (int off = 32; off > 0; off >>= 1) acc += __shfl_down(acc, off, 64);
    __shared__ float s[4];
    const int wave = t >> 6, lane = t & 63;
    if (lane == 0) s[wave] = acc;
    __syncthreads();
    if (t == 0) c[k] = (s[0] + s[1]) + (s[2] + s[3]);
}

// ---------------- Kernel 2: bterm = (sum(bias) - sum(subtract)) / N ----------------
__global__ void __launch_bounds__(256) biassum_kernel(const float* __restrict__ bias,
                                                      const float* __restrict__ subtract,
                                                      float* __restrict__ bterm) {
    const int t = threadIdx.x;
    float acc = 0.f;
    for (int i = t; i < N_DIM; i += 256) acc += bias[i] - subtract[i];
#pragma unroll
    for (int off = 32; off > 0; off >>= 1) acc += __shfl_down(acc, off, 64);
    __shared__ float s[4];
    const int wave = t >> 6, lane = t & 63;
    if (lane == 0) s[wave] = acc;
    __syncthreads();
    if (t == 0) bterm[0] = ((s[0] + s[1]) + (s[2] + s[3])) * (1.0f / (float)N_DIM);
}

// ---------------- Kernel 3: out[m][:] = x[m][:] + gelu(dot(x[m],c)/N + bterm) ----------------
// One block per row. Row (4096 f32 = 16 KiB) held in registers: 4 float4 per thread.
__global__ void __launch_bounds__(256) rowfuse_kernel(const float* __restrict__ x,
                                                      const float* __restrict__ c,
                                                      const float* __restrict__ bterm,
                                                      float* __restrict__ out) {
    const int m = blockIdx.x;
    const float4* xr = reinterpret_cast<const float4*>(x + (size_t)m * K_DIM);
    float4* orow = reinterpret_cast<float4*>(out + (size_t)m * K_DIM);
    const float4* c4 = reinterpret_cast<const float4*>(c);
    const int t = threadIdx.x;

    float4 xv[4];
    float acc = 0.f;
#pragma unroll
    for (int i = 0; i < 4; ++i) {
        xv[i] = xr[t + i * 256];
        float4 cv = c4[t + i * 256];           // L2-hit after first blocks
        acc += xv[i].x * cv.x + xv[i].y * cv.y + xv[i].z * cv.z + xv[i].w * cv.w;
    }
#pragma unroll
    for (int off = 32; off > 0; off >>= 1) acc += __shfl_down(acc, off, 64);

    __shared__ float s[4];
    __shared__ float sg;
    const int wave = t >> 6, lane = t & 63;
    if (lane == 0) s[wave] = acc;
    __syncthreads();
    if (t == 0) {
        float d = ((s[0] + s[1]) + (s[2] + s[3])) * (1.0f / (float)N_DIM) + bterm[0];
        float inner = 0.7978845608028654f * (d + 0.044715f * d * d * d);
        sg = 0.5f * d * (1.0f + tanhf(inner));
    }
    __syncthreads();
    const float g = sg;
#pragma unroll
    for (int i = 0; i < 4; ++i) {
        float4 o = xv[i];
        o.x += g; o.y += g; o.z += g; o.w += g;
        orow[t + i * 256] = o;
    }
}

extern "C" void kernel_launch(void* const* d_in, const int* in_sizes, int n_in,
                              void* d_out, int out_size, void* d_ws, size_t ws_size,
                              hipStream_t stream) {
    const float* x        = (const float*)d_in[0];   // (M, K)
    const float* W        = (const float*)d_in[1];   // (K, N)
    const float* bias     = (const float*)d_in[2];   // (N,)
    const float* subtract = (const float*)d_in[3];   // (N,)
    float* out = (float*)d_out;

    float* c     = (float*)d_ws;          // K_DIM floats
    float* bterm = c + K_DIM;             // 1 float

    const int M = in_sizes[0] / K_DIM;    // 16384

    colsum_kernel<<<K_DIM, 256, 0, stream>>>(W, c);
    biassum_kernel<<<1, 256, 0, stream>>>(bias, subtract, bterm);
    rowfuse_kernel<<<M, 256, 0, stream>>>(x, c, bterm, out);
}